// Round 1
// baseline (9167.502 us; speedup 1.0000x reference)
//
#include <hip/hip_runtime.h>
#include <math.h>

#define DIM 256
#define SEQ 2048
#define BSZ 32
#define NI  128
#define NS  4
#define N_ITERS 3

// ---------------------------------------------------------------------------
// Kernel 1: k = tokens@Wk + bk  (stored TRANSPOSED as kT[b][d][s])
//           v = tokens@Wv + bv  (stored row-major   as v[b][s][d])
// Classic 128x128x16 register-blocked SGEMM, 8x8 microtile, 256 threads.
// blockIdx.y: 0,1 -> k (n0 = y*128); 2,3 -> v (n0 = (y-2)*128)
// ---------------------------------------------------------------------------
__global__ __launch_bounds__(256) void kv_gemm(
    const float* __restrict__ tokens,
    const float* __restrict__ Wk, const float* __restrict__ bk,
    const float* __restrict__ Wv, const float* __restrict__ bv,
    float* __restrict__ kT, float* __restrict__ vout)
{
    __shared__ float As[16][132];   // A tile transposed [k][m], +4 pad
    __shared__ float Bs[16][128];   // B tile [k][n]

    const int t  = threadIdx.x;
    const int m0 = blockIdx.x * 128;
    const int yy = blockIdx.y;
    const bool isK = (yy < 2);
    const int n0 = (yy & 1) * 128;
    const float* W    = isK ? Wk : Wv;
    const float* bias = isK ? bk : bv;

    const int u = t & 15, w = t >> 4;
    // k path: microtile m <- u (coalesced kT stores over s), n <- w
    // v path: microtile n <- u (coalesced v stores over d),  m <- w
    const int am = isK ? u : w;
    const int bn = isK ? w : u;

    float acc[8][8];
#pragma unroll
    for (int i = 0; i < 8; i++)
#pragma unroll
        for (int j = 0; j < 8; j++) acc[i][j] = 0.f;

    for (int k0 = 0; k0 < 256; k0 += 16) {
#pragma unroll
        for (int p = 0; p < 2; p++) {          // A tile: 128x16 -> As[k][m]
            int idx = t + p * 256;             // 0..511 float4s
            int mm = idx >> 2, kq = idx & 3;
            const float4 av = *(const float4*)(tokens + (size_t)(m0 + mm) * 256 + k0 + kq * 4);
            As[kq * 4 + 0][mm] = av.x; As[kq * 4 + 1][mm] = av.y;
            As[kq * 4 + 2][mm] = av.z; As[kq * 4 + 3][mm] = av.w;
        }
#pragma unroll
        for (int p = 0; p < 2; p++) {          // B tile: 16x128
            int idx = t + p * 256;
            int kk = idx >> 5, nn = idx & 31;
            *(float4*)&Bs[kk][nn * 4] = *(const float4*)(W + (size_t)(k0 + kk) * 256 + n0 + nn * 4);
        }
        __syncthreads();
#pragma unroll
        for (int kk = 0; kk < 16; kk++) {
            float a[8], bb[8];
#pragma unroll
            for (int i = 0; i < 8; i++) a[i] = As[kk][am + 16 * i];
#pragma unroll
            for (int j = 0; j < 8; j++) bb[j] = Bs[kk][bn + 16 * j];
#pragma unroll
            for (int i = 0; i < 8; i++)
#pragma unroll
                for (int j = 0; j < 8; j++)
                    acc[i][j] += a[i] * bb[j];
        }
        __syncthreads();
    }

    if (isK) {
#pragma unroll
        for (int i = 0; i < 8; i++) {
            int m = m0 + u + 16 * i;
            int bb = m >> 11, s = m & 2047;
#pragma unroll
            for (int j = 0; j < 8; j++) {
                int n = n0 + w + 16 * j;
                kT[((size_t)bb * 256 + n) * 2048 + s] = acc[i][j] + bias[n];
            }
        }
    } else {
#pragma unroll
        for (int i = 0; i < 8; i++) {
            int m = m0 + w + 16 * i;
#pragma unroll
            for (int j = 0; j < 8; j++) {
                int n = n0 + u + 16 * j;
                vout[(size_t)m * 256 + n] = acc[i][j] + bias[n];
            }
        }
    }
}

// ---------------------------------------------------------------------------
// Kernel 2: qn = normalize(intent_queries), q_intent = q@Wqi + bqi,
//           cls_n = normalize(cls_embed)
// blocks 0..127: intents; 128..159: cls rows. 256 threads.
// ---------------------------------------------------------------------------
__global__ __launch_bounds__(256) void precompute(
    const float* __restrict__ cls_embed,
    const float* __restrict__ intent_q,
    const float* __restrict__ Wqi, const float* __restrict__ bqi,
    float* __restrict__ qint, float* __restrict__ qn, float* __restrict__ clsn)
{
    __shared__ float buf[256];
    __shared__ float red[4];
    const int t = threadIdx.x;
    const int blk = blockIdx.x;
    const int lane = t & 63, wv = t >> 6;

    if (blk < NI) {
        float x = intent_q[(size_t)blk * 256 + t];
        buf[t] = x;
        float ss = x * x;
#pragma unroll
        for (int m = 1; m < 64; m <<= 1) ss += __shfl_xor(ss, m, 64);
        if (lane == 0) red[wv] = ss;
        __syncthreads();
        float tot = red[0] + red[1] + red[2] + red[3];
        qn[(size_t)blk * 256 + t] = x / fmaxf(sqrtf(tot), 1e-12f);
        float acc = bqi[t];
        for (int e = 0; e < 256; e += 4) {
            const float4 q4 = *(const float4*)&buf[e];
            acc += q4.x * Wqi[(size_t)(e + 0) * 256 + t];
            acc += q4.y * Wqi[(size_t)(e + 1) * 256 + t];
            acc += q4.z * Wqi[(size_t)(e + 2) * 256 + t];
            acc += q4.w * Wqi[(size_t)(e + 3) * 256 + t];
        }
        qint[(size_t)blk * 256 + t] = acc;
    } else {
        int b = blk - NI;
        float x = cls_embed[(size_t)b * 256 + t];
        float ss = x * x;
#pragma unroll
        for (int m = 1; m < 64; m <<= 1) ss += __shfl_xor(ss, m, 64);
        if (lane == 0) red[wv] = ss;
        __syncthreads();
        float tot = red[0] + red[1] + red[2] + red[3];
        clsn[(size_t)b * 256 + t] = x / fmaxf(sqrtf(tot), 1e-12f);
    }
}

// ---------------------------------------------------------------------------
// Kernel 3: fused slot-attention. One block per (intent-group of 4, batch b).
// 512 threads = 8 waves. 16 rows = 4 intents x 4 slots.
// Logits mapping: wave w -> row-group (w>>2)*8..+7, s-slice (w&3)*64+lane.
// d-mapped phases: thread = (tcol = tid&255, half = tid>>8 -> 8 rows).
// ---------------------------------------------------------------------------
__global__ __launch_bounds__(512) void slot_attn(
    const float* __restrict__ kT,       // [B][256][2048]
    const float* __restrict__ vmat,     // [B][2048][256]
    const float* __restrict__ qint,     // [NI][256]
    const float* __restrict__ qn,       // [NI][256]
    const float* __restrict__ clsn,     // [B][256]
    const float* __restrict__ noise,    // [NI][B][NS][256]
    const float* __restrict__ slot_mu,  // [NS][256]
    const float* __restrict__ slot_sigma,
    const float* __restrict__ Wqs, const float* __restrict__ bqs,
    const float* __restrict__ ln1_g, const float* __restrict__ ln1_b,
    const float* __restrict__ ln2_g, const float* __restrict__ ln2_b,
    const float* __restrict__ Wf1, const float* __restrict__ bf1,
    const float* __restrict__ Wf2, const float* __restrict__ bf2,
    const float* __restrict__ alphap, const float* __restrict__ tempp,
    float* __restrict__ out)
{
    __shared__ float s_slots[16][256];
    __shared__ float s_qslot[16][256];   // q_slot; reused as h (LN2 out)
    __shared__ float s_p[16][256];       // softmax p tile; reused: ffn act, summ
    __shared__ float s_m[16], s_l[16], s_alpha[16];
    __shared__ float s_pmax[16][4], s_psum[16][4];
    __shared__ float s_stats[16][2];
    __shared__ float s_aw[4][4];

    const int tid  = threadIdx.x;
    const int lane = tid & 63;
    const int wv   = tid >> 6;        // 0..7
    const int half = tid >> 8;        // 0..1
    const int tcol = tid & 255;       // 0..255
    const int ig   = blockIdx.x;      // intent group 0..31
    const int b    = blockIdx.y;      // batch 0..31

    const int rb_w = (wv >> 2) * 8;   // logits: 8-row base per wave
    const int ssl  = wv & 3;          // logits: 64-wide s slice
    const int rb_h = half * 8;        // d-mapped 8-row base

    // slots init: mu + eps*sigma
#pragma unroll
    for (int j = 0; j < 8; j++) {
        int r = rb_h + j;
        int g = r >> 2, n = r & 3;
        int i = ig * 4 + g;
        float mu = slot_mu[n * 256 + tcol];
        float sg = slot_sigma[n * 256 + tcol];
        float eps = noise[(((size_t)i * BSZ + b) * NS + n) * 256 + tcol];
        s_slots[r][tcol] = mu + eps * sg;
    }

    const float* kTb = kT + (size_t)b * 256 * 2048;
    const float* vb  = vmat + (size_t)b * 2048 * 256;

    for (int it = 0; it < N_ITERS; it++) {
        if (tid < 16) { s_m[tid] = -1e30f; s_l[tid] = 0.f; }
        __syncthreads();

        // ---- Phase A: q_slot = (slots@Wqs + bqs + q_intent) * (1/16)
        {
            float acc[8];
#pragma unroll
            for (int j = 0; j < 8; j++) acc[j] = 0.f;
            for (int e = 0; e < 256; e += 4) {
                float w0 = Wqs[(size_t)(e + 0) * 256 + tcol];
                float w1 = Wqs[(size_t)(e + 1) * 256 + tcol];
                float w2 = Wqs[(size_t)(e + 2) * 256 + tcol];
                float w3 = Wqs[(size_t)(e + 3) * 256 + tcol];
#pragma unroll
                for (int j = 0; j < 8; j++) {
                    const float4 s4 = *(const float4*)&s_slots[rb_h + j][e];
                    acc[j] += s4.x * w0 + s4.y * w1 + s4.z * w2 + s4.w * w3;
                }
            }
            float bq = bqs[tcol];
#pragma unroll
            for (int j = 0; j < 8; j++) {
                int r = rb_h + j;
                int i = ig * 4 + (r >> 2);
                s_qslot[r][tcol] = (acc[j] + bq + qint[(size_t)i * 256 + tcol]) * 0.0625f;
            }
        }
        __syncthreads();

        // ---- Attention: flash-style online softmax over 8 tiles of 256
        float vacc[8];
#pragma unroll
        for (int j = 0; j < 8; j++) vacc[j] = 0.f;

        for (int s0 = 0; s0 < SEQ; s0 += 256) {
            float dot[8];
#pragma unroll
            for (int j = 0; j < 8; j++) dot[j] = 0.f;
            const float* kp = kTb + s0 + ssl * 64 + lane;
            for (int d = 0; d < 256; d += 4) {
                float k0 = kp[(size_t)(d + 0) * 2048];
                float k1 = kp[(size_t)(d + 1) * 2048];
                float k2 = kp[(size_t)(d + 2) * 2048];
                float k3 = kp[(size_t)(d + 3) * 2048];
#pragma unroll
                for (int j = 0; j < 8; j++) {
                    const float4 q4 = *(const float4*)&s_qslot[rb_w + j][d];
                    dot[j] += q4.x * k0 + q4.y * k1 + q4.z * k2 + q4.w * k3;
                }
            }
            // per-row tile max (wave butterfly) -> slice partials
#pragma unroll
            for (int j = 0; j < 8; j++) {
                float mx = dot[j];
#pragma unroll
                for (int m = 1; m < 64; m <<= 1) mx = fmaxf(mx, __shfl_xor(mx, m, 64));
                if (lane == 0) s_pmax[rb_w + j][ssl] = mx;
            }
            __syncthreads();
            if (tid < 16) {
                float tmax = fmaxf(fmaxf(s_pmax[tid][0], s_pmax[tid][1]),
                                   fmaxf(s_pmax[tid][2], s_pmax[tid][3]));
                float mold = s_m[tid];
                float mnew = fmaxf(mold, tmax);
                s_alpha[tid] = __expf(mold - mnew);
                s_m[tid] = mnew;
            }
            __syncthreads();
            // exponentiate, write p tile, slice sums
#pragma unroll
            for (int j = 0; j < 8; j++) {
                float p = __expf(dot[j] - s_m[rb_w + j]);
                s_p[rb_w + j][ssl * 64 + lane] = p;
                float sm = p;
#pragma unroll
                for (int m = 1; m < 64; m <<= 1) sm += __shfl_xor(sm, m, 64);
                if (lane == 0) s_psum[rb_w + j][ssl] = sm;
            }
            __syncthreads();
            if (tid < 16) {
                s_l[tid] = s_l[tid] * s_alpha[tid]
                         + s_psum[tid][0] + s_psum[tid][1] + s_psum[tid][2] + s_psum[tid][3];
            }
            // v accumulate (rescale + p.v)
#pragma unroll
            for (int j = 0; j < 8; j++) vacc[j] *= s_alpha[rb_h + j];
            const float* vp = vb + (size_t)s0 * 256 + tcol;
            for (int st = 0; st < 256; st += 4) {
                float v0 = vp[(size_t)(st + 0) * 256];
                float v1 = vp[(size_t)(st + 1) * 256];
                float v2 = vp[(size_t)(st + 2) * 256];
                float v3 = vp[(size_t)(st + 3) * 256];
#pragma unroll
                for (int j = 0; j < 8; j++) {
                    const float4 p4 = *(const float4*)&s_p[rb_h + j][st];
                    vacc[j] += p4.x * v0 + p4.y * v1 + p4.z * v2 + p4.w * v3;
                }
            }
            __syncthreads();
        }

        // ---- residual + LN1
        float y[8];
#pragma unroll
        for (int j = 0; j < 8; j++) {
            int r = rb_h + j;
            float upd = vacc[j] / s_l[r];
            y[j] = s_slots[r][tcol] + upd;
            s_slots[r][tcol] = y[j];
        }
        __syncthreads();
#pragma unroll
        for (int jj = 0; jj < 2; jj++) {        // wave stats: rows 2w, 2w+1
            int r = wv * 2 + jj;
            const float4 x4 = *(const float4*)&s_slots[r][lane * 4];
            float sm = x4.x + x4.y + x4.z + x4.w;
            float sq = x4.x * x4.x + x4.y * x4.y + x4.z * x4.z + x4.w * x4.w;
#pragma unroll
            for (int m = 1; m < 64; m <<= 1) { sm += __shfl_xor(sm, m, 64); sq += __shfl_xor(sq, m, 64); }
            if (lane == 0) {
                float mean = sm * (1.f / 256.f);
                float var = sq * (1.f / 256.f) - mean * mean;
                s_stats[r][0] = mean;
                s_stats[r][1] = rsqrtf(var + 1e-5f);
            }
        }
        __syncthreads();
        float x1[8];
        {
            float g1 = ln1_g[tcol], b1 = ln1_b[tcol];
#pragma unroll
            for (int j = 0; j < 8; j++) {
                int r = rb_h + j;
                x1[j] = (y[j] - s_stats[r][0]) * s_stats[r][1] * g1 + b1;
                s_slots[r][tcol] = x1[j];
            }
        }
        __syncthreads();
        // ---- LN2 stats on x1
#pragma unroll
        for (int jj = 0; jj < 2; jj++) {
            int r = wv * 2 + jj;
            const float4 x4 = *(const float4*)&s_slots[r][lane * 4];
            float sm = x4.x + x4.y + x4.z + x4.w;
            float sq = x4.x * x4.x + x4.y * x4.y + x4.z * x4.z + x4.w * x4.w;
#pragma unroll
            for (int m = 1; m < 64; m <<= 1) { sm += __shfl_xor(sm, m, 64); sq += __shfl_xor(sq, m, 64); }
            if (lane == 0) {
                float mean = sm * (1.f / 256.f);
                float var = sq * (1.f / 256.f) - mean * mean;
                s_stats[r][0] = mean;
                s_stats[r][1] = rsqrtf(var + 1e-5f);
            }
        }
        __syncthreads();
        {
            float g2 = ln2_g[tcol], b2 = ln2_b[tcol];
#pragma unroll
            for (int j = 0; j < 8; j++) {
                int r = rb_h + j;
                s_qslot[r][tcol] = (x1[j] - s_stats[r][0]) * s_stats[r][1] * g2 + b2;
            }
        }
        __syncthreads();

        // ---- FFN: chunked over the 512 hidden cols (chunks of 64)
        float ffn[8];
#pragma unroll
        for (int j = 0; j < 8; j++) ffn[j] = 0.f;
        for (int c0 = 0; c0 < 512; c0 += 64) {
            {   // act chunk: wave w -> rows 2w,2w+1; lane -> chunk col
                float a0 = 0.f, a1 = 0.f;
                int r0 = wv * 2, r1 = wv * 2 + 1;
                for (int e = 0; e < 256; e += 4) {
                    float w0 = Wf1[(size_t)(e + 0) * 512 + c0 + lane];
                    float w1 = Wf1[(size_t)(e + 1) * 512 + c0 + lane];
                    float w2 = Wf1[(size_t)(e + 2) * 512 + c0 + lane];
                    float w3 = Wf1[(size_t)(e + 3) * 512 + c0 + lane];
                    const float4 h0 = *(const float4*)&s_qslot[r0][e];
                    const float4 h1 = *(const float4*)&s_qslot[r1][e];
                    a0 += h0.x * w0 + h0.y * w1 + h0.z * w2 + h0.w * w3;
                    a1 += h1.x * w0 + h1.y * w1 + h1.z * w2 + h1.w * w3;
                }
                float bb = bf1[c0 + lane];
                float xg0 = a0 + bb, xg1 = a1 + bb;
                s_p[r0][lane] = 0.5f * xg0 * (1.f + erff(xg0 * 0.7071067811865475f));
                s_p[r1][lane] = 0.5f * xg1 * (1.f + erff(xg1 * 0.7071067811865475f));
            }
            __syncthreads();
            for (int ee = 0; ee < 64; ee += 4) {   // gemm2 partial
                float w0 = Wf2[(size_t)(c0 + ee + 0) * 256 + tcol];
                float w1 = Wf2[(size_t)(c0 + ee + 1) * 256 + tcol];
                float w2 = Wf2[(size_t)(c0 + ee + 2) * 256 + tcol];
                float w3 = Wf2[(size_t)(c0 + ee + 3) * 256 + tcol];
#pragma unroll
                for (int j = 0; j < 8; j++) {
                    const float4 p4 = *(const float4*)&s_p[rb_h + j][ee];
                    ffn[j] += p4.x * w0 + p4.y * w1 + p4.z * w2 + p4.w * w3;
                }
            }
            __syncthreads();
        }
        {
            float bb2 = bf2[tcol];
#pragma unroll
            for (int j = 0; j < 8; j++)
                s_slots[rb_h + j][tcol] = x1[j] + ffn[j] + bb2;
        }
        // next-iter top syncthreads protects s_slots
    }
    __syncthreads();

    // ---- final scoring
    const float alphav = alphap[0];
    const float tempv  = fmaxf(tempp[0], 1e-4f);

    if (wv < 4) {   // wave g handles intent g
        int g = wv;
        int i = ig * 4 + g;
        const float* qni = qn + (size_t)i * 256;
        float st[4];
#pragma unroll
        for (int j = 0; j < 4; j++) {
            const float4 x4 = *(const float4*)&s_slots[g * 4 + j][lane * 4];
            const float4 q4 = *(const float4*)(qni + lane * 4);
            float ss = x4.x * x4.x + x4.y * x4.y + x4.z * x4.z + x4.w * x4.w;
            float sq = x4.x * q4.x + x4.y * q4.y + x4.z * q4.z + x4.w * q4.w;
#pragma unroll
            for (int m = 1; m < 64; m <<= 1) { ss += __shfl_xor(ss, m, 64); sq += __shfl_xor(sq, m, 64); }
            st[j] = sq / fmaxf(sqrtf(ss), 1e-12f);
        }
        float mx = fmaxf(fmaxf(st[0], st[1]), fmaxf(st[2], st[3]));
        float e0 = __expf(st[0] - mx), e1 = __expf(st[1] - mx);
        float e2 = __expf(st[2] - mx), e3 = __expf(st[3] - mx);
        float inv = 1.f / (e0 + e1 + e2 + e3);
        if (lane == 0) {
            s_aw[g][0] = e0 * inv; s_aw[g][1] = e1 * inv;
            s_aw[g][2] = e2 * inv; s_aw[g][3] = e3 * inv;
        }
    }
    __syncthreads();
    {   // summ per intent
#pragma unroll
        for (int gg = 0; gg < 2; gg++) {
            int g = half * 2 + gg;
            float sm = s_aw[g][0] * s_slots[g * 4 + 0][tcol]
                     + s_aw[g][1] * s_slots[g * 4 + 1][tcol]
                     + s_aw[g][2] * s_slots[g * 4 + 2][tcol]
                     + s_aw[g][3] * s_slots[g * 4 + 3][tcol];
            s_p[g][tcol] = sm;
        }
    }
    __syncthreads();
    if (wv < 4) {
        int g = wv;
        int i = ig * 4 + g;
        const float4 s4 = *(const float4*)&s_p[g][lane * 4];
        const float4 q4 = *(const float4*)(qn + (size_t)i * 256 + lane * 4);
        const float4 c4 = *(const float4*)(clsn + (size_t)b * 256 + lane * 4);
        float ss = s4.x * s4.x + s4.y * s4.y + s4.z * s4.z + s4.w * s4.w;
        float sq = s4.x * q4.x + s4.y * q4.y + s4.z * q4.z + s4.w * q4.w;
        float cq = c4.x * q4.x + c4.y * q4.y + c4.z * q4.z + c4.w * q4.w;
#pragma unroll
        for (int m = 1; m < 64; m <<= 1) {
            ss += __shfl_xor(ss, m, 64);
            sq += __shfl_xor(sq, m, 64);
            cq += __shfl_xor(cq, m, 64);
        }
        if (lane == 0) {
            float score = cq + alphav * sq / fmaxf(sqrtf(ss), 1e-12f);
            out[(size_t)b * NI + i] = score / tempv;
        }
    }
}

// ---------------------------------------------------------------------------
extern "C" void kernel_launch(void* const* d_in, const int* in_sizes, int n_in,
                              void* d_out, int out_size, void* d_ws, size_t ws_size,
                              hipStream_t stream)
{
    const float* tokens     = (const float*)d_in[0];
    const float* cls_embed  = (const float*)d_in[1];
    const float* intent_q   = (const float*)d_in[2];
    const float* noise      = (const float*)d_in[3];
    const float* Wk  = (const float*)d_in[4];
    const float* bk  = (const float*)d_in[5];
    const float* Wv  = (const float*)d_in[6];
    const float* bv  = (const float*)d_in[7];
    const float* Wqs = (const float*)d_in[8];
    const float* bqs = (const float*)d_in[9];
    const float* Wqi = (const float*)d_in[10];
    const float* bqi = (const float*)d_in[11];
    const float* ln1g = (const float*)d_in[12];
    const float* ln1b = (const float*)d_in[13];
    const float* ln2g = (const float*)d_in[14];
    const float* ln2b = (const float*)d_in[15];
    const float* Wf1 = (const float*)d_in[16];
    const float* bf1 = (const float*)d_in[17];
    const float* Wf2 = (const float*)d_in[18];
    const float* bf2 = (const float*)d_in[19];
    const float* slot_mu    = (const float*)d_in[20];
    const float* slot_sigma = (const float*)d_in[21];
    const float* alphap = (const float*)d_in[22];
    const float* tempp  = (const float*)d_in[23];
    float* out = (float*)d_out;
    float* ws  = (float*)d_ws;

    // ws layout (floats): kT 16.78M | v 16.78M | qint 32K | qn 32K | clsn 8K
    float* kT   = ws;
    float* v    = ws + 16777216u;
    float* qint = ws + 33554432u;
    float* qnb  = qint + NI * 256;
    float* clsn = qnb + NI * 256;

    hipLaunchKernelGGL(kv_gemm, dim3(512, 4), dim3(256), 0, stream,
                       tokens, Wk, bk, Wv, bv, kT, v);
    hipLaunchKernelGGL(precompute, dim3(160), dim3(256), 0, stream,
                       cls_embed, intent_q, Wqi, bqi, qint, qnb, clsn);
    hipLaunchKernelGGL(slot_attn, dim3(32, 32), dim3(512), 0, stream,
                       kT, v, qint, qnb, clsn, noise, slot_mu, slot_sigma,
                       Wqs, bqs, ln1g, ln1b, ln2g, ln2b, Wf1, bf1, Wf2, bf2,
                       alphap, tempp, out);
}

// Round 2
// 1731.477 us; speedup vs baseline: 5.2946x; 5.2946x over previous
//
#include <hip/hip_runtime.h>
#include <math.h>

#define BSZ 32
#define NI  128

typedef __attribute__((ext_vector_type(8))) _Float16 f16x8;
typedef __attribute__((ext_vector_type(4))) _Float16 f16x4;
typedef __attribute__((ext_vector_type(4))) float    f32x4;

#define MFMA16(a, b, c) __builtin_amdgcn_mfma_f32_16x16x32_f16((a), (b), (c), 0, 0, 0)

__device__ inline float dot4f(float4 a, float4 b) {
    return a.x * b.x + a.y * b.y + a.z * b.z + a.w * b.w;
}

// ---------------------------------------------------------------------------
// Kernel 1: tokens f32 -> f16
// ---------------------------------------------------------------------------
__global__ __launch_bounds__(256) void tok_convert(const float* __restrict__ in,
                                                   _Float16* __restrict__ out)
{
    const int n4 = (BSZ * 2048 * 256) / 4;
    for (int i = blockIdx.x * 256 + threadIdx.x; i < n4; i += gridDim.x * 256) {
        float4 v = ((const float4*)in)[i];
        f16x4 h;
        h[0] = (_Float16)v.x; h[1] = (_Float16)v.y;
        h[2] = (_Float16)v.z; h[3] = (_Float16)v.w;
        ((f16x4*)out)[i] = h;
    }
}

// ---------------------------------------------------------------------------
// Kernel 2: prep — transposed f16 weights, qn, cls_n, qint2 = q@Wqi+bqi+bqs
// blocks: 0..255 WkT | 256..511 WvT | 512..767 WqsT | 768..1023 Wf1T |
//         1024..1535 Wf2T | 1536..1663 intents | 1664..1695 cls
// ---------------------------------------------------------------------------
__global__ __launch_bounds__(256) void prep(
    const float* __restrict__ Wk, const float* __restrict__ Wv,
    const float* __restrict__ Wqs, const float* __restrict__ Wf1,
    const float* __restrict__ Wf2,
    const float* __restrict__ intent_q, const float* __restrict__ Wqi,
    const float* __restrict__ bqi, const float* __restrict__ bqs,
    const float* __restrict__ cls_embed,
    _Float16* __restrict__ wkT, _Float16* __restrict__ wvT,
    _Float16* __restrict__ wqsT, _Float16* __restrict__ wf1T,
    _Float16* __restrict__ wf2T,
    float* __restrict__ qint2, float* __restrict__ qn, float* __restrict__ clsn)
{
    __shared__ float buf[256];
    __shared__ float red[4];
    const int t = threadIdx.x;
    const int blk = blockIdx.x;
    const int lane = t & 63, w = t >> 6;

    if (blk < 256) {                       // WkT[n][k] = Wk[k][n]
        int k = blk;
        wkT[(size_t)t * 256 + k] = (_Float16)Wk[(size_t)k * 256 + t];
    } else if (blk < 512) {
        int k = blk - 256;
        wvT[(size_t)t * 256 + k] = (_Float16)Wv[(size_t)k * 256 + t];
    } else if (blk < 768) {
        int k = blk - 512;
        wqsT[(size_t)t * 256 + k] = (_Float16)Wqs[(size_t)k * 256 + t];
    } else if (blk < 1024) {               // Wf1 [256][512] -> Wf1T [512][256]
        int k = blk - 768;
        wf1T[(size_t)t * 256 + k]         = (_Float16)Wf1[(size_t)k * 512 + t];
        wf1T[(size_t)(t + 256) * 256 + k] = (_Float16)Wf1[(size_t)k * 512 + t + 256];
    } else if (blk < 1536) {               // Wf2 [512][256] -> Wf2T [256][512]
        int k = blk - 1024;
        wf2T[(size_t)t * 512 + k] = (_Float16)Wf2[(size_t)k * 256 + t];
    } else if (blk < 1664) {               // intents
        int i = blk - 1536;
        float x = intent_q[(size_t)i * 256 + t];
        buf[t] = x;
        float ss = x * x;
#pragma unroll
        for (int m = 1; m < 64; m <<= 1) ss += __shfl_xor(ss, m, 64);
        if (lane == 0) red[w] = ss;
        __syncthreads();
        float tot = red[0] + red[1] + red[2] + red[3];
        qn[(size_t)i * 256 + t] = x / fmaxf(sqrtf(tot), 1e-12f);
        float acc = bqi[t] + bqs[t];
        for (int e = 0; e < 256; e += 4) {
            const float4 q4 = *(const float4*)&buf[e];
            acc += q4.x * Wqi[(size_t)(e + 0) * 256 + t];
            acc += q4.y * Wqi[(size_t)(e + 1) * 256 + t];
            acc += q4.z * Wqi[(size_t)(e + 2) * 256 + t];
            acc += q4.w * Wqi[(size_t)(e + 3) * 256 + t];
        }
        qint2[(size_t)i * 256 + t] = acc;
    } else {                               // cls
        int b = blk - 1664;
        float x = cls_embed[(size_t)b * 256 + t];
        float ss = x * x;
#pragma unroll
        for (int m = 1; m < 64; m <<= 1) ss += __shfl_xor(ss, m, 64);
        if (lane == 0) red[w] = ss;
        __syncthreads();
        float tot = red[0] + red[1] + red[2] + red[3];
        clsn[(size_t)b * 256 + t] = x / fmaxf(sqrtf(tot), 1e-12f);
    }
}

// ---------------------------------------------------------------------------
// Kernel 3: kv projection, MFMA f16. A-frags from global tokens_f16, B-frags
// from transposed weights. Outputs k16[b][s][d], vT16[b][d][s].
// 1024 blocks x 256 thr (4 waves); wave -> one 16-row m-tile.
// ---------------------------------------------------------------------------
__global__ __launch_bounds__(256) void kv_gemm(
    const _Float16* __restrict__ tok,
    const _Float16* __restrict__ wkT, const _Float16* __restrict__ wvT,
    const float* __restrict__ bk, const float* __restrict__ bv,
    _Float16* __restrict__ k16, _Float16* __restrict__ vT16)
{
    const int lane = threadIdx.x & 63, wvi = threadIdx.x >> 6;
    const int l15 = lane & 15, quad = lane >> 4;
    const int mt = blockIdx.x * 4 + wvi;       // 0..4095
    const int m0 = mt * 16;
    const int bb = m0 >> 11;                   // batch
    const int sbase = m0 & 2047;

    f16x8 a[8];
    const _Float16* arow = tok + (size_t)(m0 + l15) * 256 + quad * 8;
#pragma unroll
    for (int ks = 0; ks < 8; ks++) a[ks] = *(const f16x8*)(arow + ks * 32);

    for (int path = 0; path < 2; path++) {
        const _Float16* wT = path ? wvT : wkT;
        const float* bias = path ? bv : bk;
        for (int np = 0; np < 8; np++) {
            const int nt0 = np * 2, nt1 = np * 2 + 1;
            f32x4 c0 = {0.f, 0.f, 0.f, 0.f}, c1 = {0.f, 0.f, 0.f, 0.f};
#pragma unroll
            for (int ks = 0; ks < 8; ks++) {
                f16x8 b0 = *(const f16x8*)(wT + (size_t)(nt0 * 16 + l15) * 256 + ks * 32 + quad * 8);
                f16x8 b1 = *(const f16x8*)(wT + (size_t)(nt1 * 16 + l15) * 256 + ks * 32 + quad * 8);
                c0 = MFMA16(a[ks], b0, c0);
                c1 = MFMA16(a[ks], b1, c1);
            }
            if (path == 0) {   // k16[b][s][d], scalar f16 stores
#pragma unroll
                for (int reg = 0; reg < 4; reg++) {
                    int s = sbase + quad * 4 + reg;
                    int col0 = nt0 * 16 + l15, col1 = nt1 * 16 + l15;
                    k16[((size_t)bb * 2048 + s) * 256 + col0] = (_Float16)(c0[reg] + bias[col0]);
                    k16[((size_t)bb * 2048 + s) * 256 + col1] = (_Float16)(c1[reg] + bias[col1]);
                }
            } else {           // vT16[b][d][s], 4 consecutive s -> 8B store
                int col0 = nt0 * 16 + l15, col1 = nt1 * 16 + l15;
                float bi0 = bias[col0], bi1 = bias[col1];
                f16x4 p0, p1;
#pragma unroll
                for (int reg = 0; reg < 4; reg++) {
                    p0[reg] = (_Float16)(c0[reg] + bi0);
                    p1[reg] = (_Float16)(c1[reg] + bi1);
                }
                int s0 = sbase + quad * 4;
                *(f16x4*)(vT16 + ((size_t)bb * 256 + col0) * 2048 + s0) = p0;
                *(f16x4*)(vT16 + ((size_t)bb * 256 + col1) * 2048 + s0) = p1;
            }
        }
    }
}

// ---------------------------------------------------------------------------
// Kernel 4: fused slot attention, MFMA f16.
// Block = (batch b, 8 intents) -> 32 rows. 512 thr = 8 waves. 512 blocks.
// MFMA tile ownership (all phases): mt = wv&1 (row-halves), g4 = wv>>1.
// s-tiles of 128 with online softmax; FFN in 4 chunks of 128 cols.
// LDS ~59KB -> 2 blocks/CU.
// ---------------------------------------------------------------------------
__global__ __launch_bounds__(512, 4) void slot_attn(
    const _Float16* __restrict__ k16,   // [B][2048][256]
    const _Float16* __restrict__ vT16,  // [B][256][2048]
    const _Float16* __restrict__ wqsT,  // [256][256]
    const _Float16* __restrict__ wf1T,  // [512][256]
    const _Float16* __restrict__ wf2T,  // [256][512]
    const float* __restrict__ qint2,    // [NI][256]
    const float* __restrict__ qn,       // [NI][256]
    const float* __restrict__ clsn,     // [B][256]
    const float* __restrict__ noise,    // [NI][B][4][256]
    const float* __restrict__ slot_mu, const float* __restrict__ slot_sigma,
    const float* __restrict__ ln1_g, const float* __restrict__ ln1_b,
    const float* __restrict__ ln2_g, const float* __restrict__ ln2_b,
    const float* __restrict__ bf1, const float* __restrict__ bf2,
    const float* __restrict__ alphap, const float* __restrict__ tempp,
    float* __restrict__ out)
{
    __shared__ __align__(16) float    s_slots[32 * 260];   // 33280 B
    __shared__ __align__(16) _Float16 s_q[32 * 264];       // 16896 B
    __shared__ __align__(16) _Float16 s_p[32 * 136];       //  8704 B
    __shared__ float s_redA[32 * 4], s_redB[32 * 4];
    __shared__ float s_m[32], s_l[32], s_alpha[32];

    const int tid = threadIdx.x, lane = tid & 63, wvi = tid >> 6;
    const int l15 = lane & 15, quad = lane >> 4;
    const int mt = wvi & 1, g4 = wvi >> 1;

    // XCD-aware decode: 4 distinct b per XCD
    const int x = blockIdx.x, c8 = x & 7, t = x >> 3;
    const int b = (t >> 4) * 8 + c8;
    const int i0 = (t & 15) * 8;

    // init slots = mu + eps*sigma (d-mapped)
    {
        const int tcol = tid & 255, hh = tid >> 8;
#pragma unroll
        for (int j = 0; j < 16; j++) {
            int r = hh * 16 + j;
            int ii = r >> 2, n = r & 3, i = i0 + ii;
            s_slots[r * 260 + tcol] = slot_mu[n * 256 + tcol]
                + noise[(((size_t)i * BSZ + b) * 4 + n) * 256 + tcol] * slot_sigma[n * 256 + tcol];
        }
    }
    const _Float16* kB = k16 + (size_t)b * 2048 * 256;
    const _Float16* vB = vT16 + (size_t)b * 256 * 2048;

    for (int it = 0; it < 3; it++) {
        __syncthreads();   // slots ready
        // ---- Phase A: q_slot = (slots@Wqs + bqs + qint)*(1/16) -> s_q f16
        {
            f16x8 af[8];
#pragma unroll
            for (int ks = 0; ks < 8; ks++) {
                const float* sp = &s_slots[(mt * 16 + l15) * 260 + ks * 32 + quad * 8];
                float4 v0 = *(const float4*)sp, v1 = *(const float4*)(sp + 4);
                f16x8 h;
                h[0] = (_Float16)v0.x; h[1] = (_Float16)v0.y; h[2] = (_Float16)v0.z; h[3] = (_Float16)v0.w;
                h[4] = (_Float16)v1.x; h[5] = (_Float16)v1.y; h[6] = (_Float16)v1.z; h[7] = (_Float16)v1.w;
                af[ks] = h;
            }
#pragma unroll
            for (int u = 0; u < 4; u++) {
                int nt = g4 + 4 * u;
                f32x4 cc = {0.f, 0.f, 0.f, 0.f};
#pragma unroll
                for (int ks = 0; ks < 8; ks++)
                    cc = MFMA16(af[ks], *(const f16x8*)(wqsT + (size_t)(nt * 16 + l15) * 256 + ks * 32 + quad * 8), cc);
#pragma unroll
                for (int reg = 0; reg < 4; reg++) {
                    int row = mt * 16 + quad * 4 + reg, col = nt * 16 + l15;
                    int i = i0 + (row >> 2);
                    s_q[row * 264 + col] = (_Float16)((cc[reg] + qint2[(size_t)i * 256 + col]) * 0.0625f);
                }
            }
        }
        if (tid < 32) { s_m[tid] = -1e30f; s_l[tid] = 0.f; }
        f32x4 cpv[4];
#pragma unroll
        for (int u = 0; u < 4; u++) cpv[u] = (f32x4){0.f, 0.f, 0.f, 0.f};
        __syncthreads();   // s_q + m/l ready

        // hoisted logits A-frags (s_q constant over tiles)
        f16x8 aq[8];
#pragma unroll
        for (int ks = 0; ks < 8; ks++)
            aq[ks] = *(const f16x8*)&s_q[(mt * 16 + l15) * 264 + ks * 32 + quad * 8];

        // ---- attention: 16 s-tiles of 128, online softmax
        for (int st = 0; st < 16; st++) {
            const int s0 = st * 128;
            f32x4 cl[2];
#pragma unroll
            for (int u = 0; u < 2; u++) {
                int s16 = g4 + 4 * u;
                cl[u] = (f32x4){0.f, 0.f, 0.f, 0.f};
#pragma unroll
                for (int ks = 0; ks < 8; ks++)
                    cl[u] = MFMA16(aq[ks],
                        *(const f16x8*)(kB + (size_t)(s0 + s16 * 16 + l15) * 256 + ks * 32 + quad * 8), cl[u]);
            }
            // row-max partials
            float mx[4];
#pragma unroll
            for (int reg = 0; reg < 4; reg++) mx[reg] = fmaxf(cl[0][reg], cl[1][reg]);
#pragma unroll
            for (int msk = 1; msk <= 8; msk <<= 1)
#pragma unroll
                for (int reg = 0; reg < 4; reg++) mx[reg] = fmaxf(mx[reg], __shfl_xor(mx[reg], msk, 64));
            if (l15 == 0) {
#pragma unroll
                for (int reg = 0; reg < 4; reg++) s_redA[(mt * 16 + quad * 4 + reg) * 4 + g4] = mx[reg];
            }
            __syncthreads();   // (1)
            if (tid < 32) {
                float tm = fmaxf(fmaxf(s_redA[tid * 4], s_redA[tid * 4 + 1]),
                                 fmaxf(s_redA[tid * 4 + 2], s_redA[tid * 4 + 3]));
                float mo = s_m[tid], mn = fmaxf(mo, tm);
                s_m[tid] = mn;
                s_alpha[tid] = __expf(mo - mn);
            }
            __syncthreads();   // (2)
            // p, sum partials, rescale cpv
            float rowm[4], sm[4];
#pragma unroll
            for (int reg = 0; reg < 4; reg++) { rowm[reg] = s_m[mt * 16 + quad * 4 + reg]; sm[reg] = 0.f; }
#pragma unroll
            for (int u = 0; u < 2; u++) {
                int s16 = g4 + 4 * u;
#pragma unroll
                for (int reg = 0; reg < 4; reg++) {
                    float p = __expf(cl[u][reg] - rowm[reg]);
                    sm[reg] += p;
                    s_p[(mt * 16 + quad * 4 + reg) * 136 + s16 * 16 + l15] = (_Float16)p;
                }
            }
#pragma unroll
            for (int msk = 1; msk <= 8; msk <<= 1)
#pragma unroll
                for (int reg = 0; reg < 4; reg++) sm[reg] += __shfl_xor(sm[reg], msk, 64);
            if (l15 == 0) {
#pragma unroll
                for (int reg = 0; reg < 4; reg++) s_redB[(mt * 16 + quad * 4 + reg) * 4 + g4] = sm[reg];
            }
            float al[4];
#pragma unroll
            for (int reg = 0; reg < 4; reg++) al[reg] = s_alpha[mt * 16 + quad * 4 + reg];
#pragma unroll
            for (int u = 0; u < 4; u++)
#pragma unroll
                for (int reg = 0; reg < 4; reg++) cpv[u][reg] *= al[reg];
            __syncthreads();   // (3) p-writes visible
            if (tid < 32)
                s_l[tid] = s_l[tid] * s_alpha[tid]
                         + s_redB[tid * 4] + s_redB[tid * 4 + 1] + s_redB[tid * 4 + 2] + s_redB[tid * 4 + 3];
            // PV accumulate
            f16x8 ap[4];
#pragma unroll
            for (int ks = 0; ks < 4; ks++)
                ap[ks] = *(const f16x8*)&s_p[(mt * 16 + l15) * 136 + ks * 32 + quad * 8];
#pragma unroll
            for (int u = 0; u < 4; u++) {
                int dt = g4 + 4 * u;
#pragma unroll
                for (int ks = 0; ks < 4; ks++)
                    cpv[u] = MFMA16(ap[ks],
                        *(const f16x8*)(vB + (size_t)(dt * 16 + l15) * 2048 + s0 + ks * 32 + quad * 8), cpv[u]);
            }
        }
        __syncthreads();   // s_l final, PV done

        // ---- residual: slots += upd
        {
            float invl[4];
#pragma unroll
            for (int reg = 0; reg < 4; reg++) invl[reg] = 1.f / s_l[mt * 16 + quad * 4 + reg];
#pragma unroll
            for (int u = 0; u < 4; u++)
#pragma unroll
                for (int reg = 0; reg < 4; reg++) {
                    int row = mt * 16 + quad * 4 + reg, col = (g4 + 4 * u) * 16 + l15;
                    s_slots[row * 260 + col] += cpv[u][reg] * invl[reg];
                }
        }
        __syncthreads();

        // ---- LN1 -> x1 (into s_slots), LN2 -> h f16 (into s_q); wave -> 4 rows
        {
            float4 g1v = *(const float4*)(ln1_g + lane * 4);
            float4 b1v = *(const float4*)(ln1_b + lane * 4);
            float4 g2v = *(const float4*)(ln2_g + lane * 4);
            float4 b2v = *(const float4*)(ln2_b + lane * 4);
#pragma unroll
            for (int jr = 0; jr < 4; jr++) {
                int row = wvi * 4 + jr;
                float4 y = *(const float4*)&s_slots[row * 260 + lane * 4];
                float sm1 = y.x + y.y + y.z + y.w;
                float sq1 = dot4f(y, y);
#pragma unroll
                for (int m = 1; m < 64; m <<= 1) { sm1 += __shfl_xor(sm1, m, 64); sq1 += __shfl_xor(sq1, m, 64); }
                float mean = sm1 * (1.f / 256.f);
                float rstd = rsqrtf(sq1 * (1.f / 256.f) - mean * mean + 1e-5f);
                float4 x1;
                x1.x = (y.x - mean) * rstd * g1v.x + b1v.x;
                x1.y = (y.y - mean) * rstd * g1v.y + b1v.y;
                x1.z = (y.z - mean) * rstd * g1v.z + b1v.z;
                x1.w = (y.w - mean) * rstd * g1v.w + b1v.w;
                *(float4*)&s_slots[row * 260 + lane * 4] = x1;
                float sm2 = x1.x + x1.y + x1.z + x1.w;
                float sq2 = dot4f(x1, x1);
#pragma unroll
                for (int m = 1; m < 64; m <<= 1) { sm2 += __shfl_xor(sm2, m, 64); sq2 += __shfl_xor(sq2, m, 64); }
                float mean2 = sm2 * (1.f / 256.f);
                float rstd2 = rsqrtf(sq2 * (1.f / 256.f) - mean2 * mean2 + 1e-5f);
                f16x4 h;
                h[0] = (_Float16)((x1.x - mean2) * rstd2 * g2v.x + b2v.x);
                h[1] = (_Float16)((x1.y - mean2) * rstd2 * g2v.y + b2v.y);
                h[2] = (_Float16)((x1.z - mean2) * rstd2 * g2v.z + b2v.z);
                h[3] = (_Float16)((x1.w - mean2) * rstd2 * g2v.w + b2v.w);
                *(f16x4*)&s_q[row * 264 + lane * 4] = h;
            }
        }
        __syncthreads();

        // ---- FFN: 4 chunks of 128 hidden cols
        f32x4 c2[4];
#pragma unroll
        for (int u = 0; u < 4; u++) c2[u] = (f32x4){0.f, 0.f, 0.f, 0.f};
        f16x8 ah[8];
#pragma unroll
        for (int ks = 0; ks < 8; ks++)
            ah[ks] = *(const f16x8*)&s_q[(mt * 16 + l15) * 264 + ks * 32 + quad * 8];
        for (int ch = 0; ch < 4; ch++) {
#pragma unroll
            for (int u = 0; u < 2; u++) {
                int nt = g4 + 4 * u;                       // 0..7
                f32x4 ca = {0.f, 0.f, 0.f, 0.f};
#pragma unroll
                for (int ks = 0; ks < 8; ks++)
                    ca = MFMA16(ah[ks],
                        *(const f16x8*)(wf1T + (size_t)(ch * 128 + nt * 16 + l15) * 256 + ks * 32 + quad * 8), ca);
#pragma unroll
                for (int reg = 0; reg < 4; reg++) {
                    int row = mt * 16 + quad * 4 + reg, col = nt * 16 + l15;
                    float xg = ca[reg] + bf1[ch * 128 + col];
                    float ge = 0.5f * xg * (1.f + erff(xg * 0.70710678118654752f));
                    s_p[row * 136 + col] = (_Float16)ge;
                }
            }
            __syncthreads();
            f16x8 apf[4];
#pragma unroll
            for (int ks = 0; ks < 4; ks++)
                apf[ks] = *(const f16x8*)&s_p[(mt * 16 + l15) * 136 + ks * 32 + quad * 8];
#pragma unroll
            for (int u = 0; u < 4; u++) {
                int ntd = g4 + 4 * u;
#pragma unroll
                for (int ks = 0; ks < 4; ks++)
                    c2[u] = MFMA16(apf[ks],
                        *(const f16x8*)(wf2T + (size_t)(ntd * 16 + l15) * 512 + ch * 128 + ks * 32 + quad * 8), c2[u]);
            }
            __syncthreads();
        }
        // slots = x1 + ffn + bf2
#pragma unroll
        for (int u = 0; u < 4; u++)
#pragma unroll
            for (int reg = 0; reg < 4; reg++) {
                int row = mt * 16 + quad * 4 + reg, col = (g4 + 4 * u) * 16 + l15;
                s_slots[row * 260 + col] += c2[u][reg] + bf2[col];
            }
    }
    __syncthreads();

    // ---- final scoring: wave wvi -> intent i0+wvi
    {
        const int i = i0 + wvi;
        float4 qv = *(const float4*)(qn + (size_t)i * 256 + lane * 4);
        float4 xs[4];
        float st4[4];
#pragma unroll
        for (int n = 0; n < 4; n++) {
            xs[n] = *(const float4*)&s_slots[(wvi * 4 + n) * 260 + lane * 4];
            float ss = dot4f(xs[n], xs[n]);
            float sq = dot4f(xs[n], qv);
#pragma unroll
            for (int m = 1; m < 64; m <<= 1) { ss += __shfl_xor(ss, m, 64); sq += __shfl_xor(sq, m, 64); }
            st4[n] = sq / fmaxf(sqrtf(ss), 1e-12f);
        }
        float mxs = fmaxf(fmaxf(st4[0], st4[1]), fmaxf(st4[2], st4[3]));
        float e0 = __expf(st4[0] - mxs), e1 = __expf(st4[1] - mxs);
        float e2 = __expf(st4[2] - mxs), e3 = __expf(st4[3] - mxs);
        float inv = 1.f / (e0 + e1 + e2 + e3);
        float4 smv;
        smv.x = (e0 * xs[0].x + e1 * xs[1].x + e2 * xs[2].x + e3 * xs[3].x) * inv;
        smv.y = (e0 * xs[0].y + e1 * xs[1].y + e2 * xs[2].y + e3 * xs[3].y) * inv;
        smv.z = (e0 * xs[0].z + e1 * xs[1].z + e2 * xs[2].z + e3 * xs[3].z) * inv;
        smv.w = (e0 * xs[0].w + e1 * xs[1].w + e2 * xs[2].w + e3 * xs[3].w) * inv;
        float ssm = dot4f(smv, smv);
        float sqn = dot4f(smv, qv);
        float4 cv = *(const float4*)(clsn + (size_t)b * 256 + lane * 4);
        float cq = dot4f(cv, qv);
#pragma unroll
        for (int m = 1; m < 64; m <<= 1) {
            ssm += __shfl_xor(ssm, m, 64);
            sqn += __shfl_xor(sqn, m, 64);
            cq  += __shfl_xor(cq,  m, 64);
        }
        if (lane == 0) {
            float score = cq + alphap[0] * sqn / fmaxf(sqrtf(ssm), 1e-12f);
            out[(size_t)b * NI + i] = score / fmaxf(tempp[0], 1e-4f);
        }
    }
}

// ---------------------------------------------------------------------------
extern "C" void kernel_launch(void* const* d_in, const int* in_sizes, int n_in,
                              void* d_out, int out_size, void* d_ws, size_t ws_size,
                              hipStream_t stream)
{
    const float* tokens     = (const float*)d_in[0];
    const float* cls_embed  = (const float*)d_in[1];
    const float* intent_q   = (const float*)d_in[2];
    const float* noise      = (const float*)d_in[3];
    const float* Wk  = (const float*)d_in[4];
    const float* bk  = (const float*)d_in[5];
    const float* Wv  = (const float*)d_in[6];
    const float* bv  = (const float*)d_in[7];
    const float* Wqs = (const float*)d_in[8];
    const float* bqs = (const float*)d_in[9];
    const float* Wqi = (const float*)d_in[10];
    const float* bqi = (const float*)d_in[11];
    const float* ln1g = (const float*)d_in[12];
    const float* ln1b = (const float*)d_in[13];
    const float* ln2g = (const float*)d_in[14];
    const float* ln2b = (const float*)d_in[15];
    const float* Wf1 = (const float*)d_in[16];
    const float* bf1 = (const float*)d_in[17];
    const float* Wf2 = (const float*)d_in[18];
    const float* bf2 = (const float*)d_in[19];
    const float* slot_mu    = (const float*)d_in[20];
    const float* slot_sigma = (const float*)d_in[21];
    const float* alphap = (const float*)d_in[22];
    const float* tempp  = (const float*)d_in[23];
    float* out = (float*)d_out;

    char* base = (char*)d_ws;
    _Float16* tok16 = (_Float16*)(base);                       // 33554432 B
    _Float16* k16   = (_Float16*)(base + 33554432u);           // 33554432 B
    _Float16* vT16  = (_Float16*)(base + 67108864u);           // 33554432 B
    _Float16* wkT   = (_Float16*)(base + 100663296u);          // 131072 B
    _Float16* wvT   = (_Float16*)(base + 100794368u);
    _Float16* wqsT  = (_Float16*)(base + 100925440u);
    _Float16* wf1T  = (_Float16*)(base + 101056512u);          // 262144 B
    _Float16* wf2T  = (_Float16*)(base + 101318656u);          // 262144 B
    float* qint2 = (float*)(base + 101580800u);                // 131072 B
    float* qnb   = (float*)(base + 101711872u);                // 131072 B
    float* clsn  = (float*)(base + 101843968u);                // 32768 B

    tok_convert<<<2048, 256, 0, stream>>>(tokens, tok16);
    prep<<<1696, 256, 0, stream>>>(Wk, Wv, Wqs, Wf1, Wf2, intent_q, Wqi, bqi, bqs,
                                   cls_embed, wkT, wvT, wqsT, wf1T, wf2T,
                                   qint2, qnb, clsn);
    kv_gemm<<<1024, 256, 0, stream>>>(tok16, wkT, wvT, bk, bv, k16, vT16);
    slot_attn<<<512, 512, 0, stream>>>(k16, vT16, wqsT, wf1T, wf2T, qint2, qnb, clsn,
                                       noise, slot_mu, slot_sigma, ln1g, ln1b, ln2g, ln2b,
                                       bf1, bf2, alphap, tempp, out);
}

// Round 3
// 1285.479 us; speedup vs baseline: 7.1316x; 1.3470x over previous
//
#include <hip/hip_runtime.h>
#include <math.h>

#define BSZ 32
#define NI  128

typedef __attribute__((ext_vector_type(8))) _Float16 f16x8;
typedef __attribute__((ext_vector_type(4))) _Float16 f16x4;
typedef __attribute__((ext_vector_type(4))) float    f32x4;

#define MFMA16(a, b, c) __builtin_amdgcn_mfma_f32_16x16x32_f16((a), (b), (c), 0, 0, 0)

// ---------------------------------------------------------------------------
// Kernel 1: tokens f32 -> f16
// ---------------------------------------------------------------------------
__global__ __launch_bounds__(256) void tok_convert(const float* __restrict__ in,
                                                   _Float16* __restrict__ out)
{
    const int n4 = (BSZ * 2048 * 256) / 4;
    for (int i = blockIdx.x * 256 + threadIdx.x; i < n4; i += gridDim.x * 256) {
        float4 v = ((const float4*)in)[i];
        f16x4 h;
        h[0] = (_Float16)v.x; h[1] = (_Float16)v.y;
        h[2] = (_Float16)v.z; h[3] = (_Float16)v.w;
        ((f16x4*)out)[i] = h;
    }
}

// ---------------------------------------------------------------------------
// Kernel 2: prep — transposed f16 weights, qn, cls_n, qint2 = q@Wqi+bqi+bqs
// ---------------------------------------------------------------------------
__global__ __launch_bounds__(256) void prep(
    const float* __restrict__ Wk, const float* __restrict__ Wv,
    const float* __restrict__ Wqs, const float* __restrict__ Wf1,
    const float* __restrict__ Wf2,
    const float* __restrict__ intent_q, const float* __restrict__ Wqi,
    const float* __restrict__ bqi, const float* __restrict__ bqs,
    const float* __restrict__ cls_embed,
    _Float16* __restrict__ wkT, _Float16* __restrict__ wvT,
    _Float16* __restrict__ wqsT, _Float16* __restrict__ wf1T,
    _Float16* __restrict__ wf2T,
    float* __restrict__ qint2, float* __restrict__ qn, float* __restrict__ clsn)
{
    __shared__ float buf[256];
    __shared__ float red[4];
    const int t = threadIdx.x;
    const int blk = blockIdx.x;
    const int lane = t & 63, w = t >> 6;

    if (blk < 256) {
        int k = blk;
        wkT[(size_t)t * 256 + k] = (_Float16)Wk[(size_t)k * 256 + t];
    } else if (blk < 512) {
        int k = blk - 256;
        wvT[(size_t)t * 256 + k] = (_Float16)Wv[(size_t)k * 256 + t];
    } else if (blk < 768) {
        int k = blk - 512;
        wqsT[(size_t)t * 256 + k] = (_Float16)Wqs[(size_t)k * 256 + t];
    } else if (blk < 1024) {
        int k = blk - 768;
        wf1T[(size_t)t * 256 + k]         = (_Float16)Wf1[(size_t)k * 512 + t];
        wf1T[(size_t)(t + 256) * 256 + k] = (_Float16)Wf1[(size_t)k * 512 + t + 256];
    } else if (blk < 1536) {
        int k = blk - 1024;
        wf2T[(size_t)t * 512 + k] = (_Float16)Wf2[(size_t)k * 256 + t];
    } else if (blk < 1664) {
        int i = blk - 1536;
        float x = intent_q[(size_t)i * 256 + t];
        buf[t] = x;
        float ss = x * x;
#pragma unroll
        for (int m = 1; m < 64; m <<= 1) ss += __shfl_xor(ss, m, 64);
        if (lane == 0) red[w] = ss;
        __syncthreads();
        float tot = red[0] + red[1] + red[2] + red[3];
        qn[(size_t)i * 256 + t] = x / fmaxf(sqrtf(tot), 1e-12f);
        float acc = bqi[t] + bqs[t];
        for (int e = 0; e < 256; e += 4) {
            const float4 q4 = *(const float4*)&buf[e];
            acc += q4.x * Wqi[(size_t)(e + 0) * 256 + t];
            acc += q4.y * Wqi[(size_t)(e + 1) * 256 + t];
            acc += q4.z * Wqi[(size_t)(e + 2) * 256 + t];
            acc += q4.w * Wqi[(size_t)(e + 3) * 256 + t];
        }
        qint2[(size_t)i * 256 + t] = acc;
    } else {
        int b = blk - 1664;
        float x = cls_embed[(size_t)b * 256 + t];
        float ss = x * x;
#pragma unroll
        for (int m = 1; m < 64; m <<= 1) ss += __shfl_xor(ss, m, 64);
        if (lane == 0) red[w] = ss;
        __syncthreads();
        float tot = red[0] + red[1] + red[2] + red[3];
        clsn[(size_t)b * 256 + t] = x / fmaxf(sqrtf(tot), 1e-12f);
    }
}

// ---------------------------------------------------------------------------
// Kernel 3a: k = tok@Wk + bk -> k16[b][s][d]. MFMA with m=d, n=s so the 4
// C-regs (consecutive d) pack into one 8B store. 2048 blocks x 64 thr.
// block = (b, d-pair mp 0..7, s-eighth se 0..7)
// ---------------------------------------------------------------------------
__global__ __launch_bounds__(64) void k_proj(
    const _Float16* __restrict__ tok, const _Float16* __restrict__ wkT,
    const float* __restrict__ bk, _Float16* __restrict__ k16)
{
    const int lane = threadIdx.x, l15 = lane & 15, quad = lane >> 4;
    const int blk = blockIdx.x;
    const int b = blk >> 6, mp = (blk >> 3) & 7, se = blk & 7;
    const _Float16* tb = tok + (size_t)b * 2048 * 256;

    f16x8 a0[8], a1[8];
#pragma unroll
    for (int ks = 0; ks < 8; ks++) {
        a0[ks] = *(const f16x8*)(wkT + (size_t)(mp * 32 + l15) * 256 + ks * 32 + quad * 8);
        a1[ks] = *(const f16x8*)(wkT + (size_t)(mp * 32 + 16 + l15) * 256 + ks * 32 + quad * 8);
    }
    f32x4 bi0 = *(const f32x4*)(bk + mp * 32 + quad * 4);
    f32x4 bi1 = *(const f32x4*)(bk + mp * 32 + 16 + quad * 4);

    for (int nt = 0; nt < 16; nt++) {
        int s = se * 256 + nt * 16 + l15;
        f32x4 c0 = {0.f, 0.f, 0.f, 0.f}, c1 = {0.f, 0.f, 0.f, 0.f};
#pragma unroll
        for (int ks = 0; ks < 8; ks++) {
            f16x8 bf = *(const f16x8*)(tb + (size_t)s * 256 + ks * 32 + quad * 8);
            c0 = MFMA16(a0[ks], bf, c0);
            c1 = MFMA16(a1[ks], bf, c1);
        }
        f16x4 p0, p1;
#pragma unroll
        for (int reg = 0; reg < 4; reg++) {
            p0[reg] = (_Float16)(c0[reg] + bi0[reg]);
            p1[reg] = (_Float16)(c1[reg] + bi1[reg]);
        }
        _Float16* kp = k16 + ((size_t)b * 2048 + s) * 256 + mp * 32 + quad * 4;
        *(f16x4*)kp = p0;
        *(f16x4*)(kp + 16) = p1;
    }
}

// ---------------------------------------------------------------------------
// Kernel 3b: v = tok@Wv + bv -> vT16[b][d][s]. m=s, n=d; C-regs = consecutive
// s pack into 8B stores of the transposed layout. 2048 blocks x 64 thr.
// block = (b, s-pair sp 0..63)
// ---------------------------------------------------------------------------
__global__ __launch_bounds__(64) void v_proj(
    const _Float16* __restrict__ tok, const _Float16* __restrict__ wvT,
    const float* __restrict__ bv, _Float16* __restrict__ vT16)
{
    const int lane = threadIdx.x, l15 = lane & 15, quad = lane >> 4;
    const int blk = blockIdx.x;
    const int b = blk >> 6, sp = blk & 63;
    const _Float16* tb = tok + (size_t)b * 2048 * 256;

    f16x8 a0[8], a1[8];
#pragma unroll
    for (int ks = 0; ks < 8; ks++) {
        a0[ks] = *(const f16x8*)(tb + (size_t)(sp * 32 + l15) * 256 + ks * 32 + quad * 8);
        a1[ks] = *(const f16x8*)(tb + (size_t)(sp * 32 + 16 + l15) * 256 + ks * 32 + quad * 8);
    }
    for (int nt = 0; nt < 16; nt++) {
        int d = nt * 16 + l15;
        f32x4 c0 = {0.f, 0.f, 0.f, 0.f}, c1 = {0.f, 0.f, 0.f, 0.f};
#pragma unroll
        for (int ks = 0; ks < 8; ks++) {
            f16x8 bf = *(const f16x8*)(wvT + (size_t)d * 256 + ks * 32 + quad * 8);
            c0 = MFMA16(a0[ks], bf, c0);
            c1 = MFMA16(a1[ks], bf, c1);
        }
        float bb = bv[d];
        f16x4 p0, p1;
#pragma unroll
        for (int reg = 0; reg < 4; reg++) {
            p0[reg] = (_Float16)(c0[reg] + bb);
            p1[reg] = (_Float16)(c1[reg] + bb);
        }
        _Float16* vp = vT16 + ((size_t)b * 256 + d) * 2048 + sp * 32 + quad * 4;
        *(f16x4*)vp = p0;
        *(f16x4*)(vp + 16) = p1;
    }
}

// ---------------------------------------------------------------------------
// Kernel 4: fused slot attention v3.
// 256 blocks x 256 thr (4 waves). Block = (b, 16 intents) = 64 rows.
// Each wave owns 16 rows (4 intents x 4 slots) fully in registers:
//   sl[16] f32x4 = slots (C-layout: row=quad*4+reg, col=u*16+l15)
// Wave-local online softmax (quad shuffles, zero cross-wave reductions).
// k/v staged to LDS per 32-s chunk (shared x4 waves, 2 barriers/chunk).
// Wqs/FFN per-wave m-split, A-frags hoisted, staging arena reused as scratch.
// LDS 42.5 KB -> 2 blocks/CU target.
// ---------------------------------------------------------------------------
__global__ __launch_bounds__(256, 2) void slot_attn(
    const _Float16* __restrict__ k16,   // [B][2048][256]
    const _Float16* __restrict__ vT16,  // [B][256][2048]
    const _Float16* __restrict__ wqsT,  // [256][256]
    const _Float16* __restrict__ wf1T,  // [512][256]
    const _Float16* __restrict__ wf2T,  // [256][512]
    const float* __restrict__ qint2,    // [NI][256] (includes bqs+bqi)
    const float* __restrict__ qn,       // [NI][256]
    const float* __restrict__ clsn,     // [B][256]
    const float* __restrict__ noise,    // [NI][B][4][256]
    const float* __restrict__ slot_mu, const float* __restrict__ slot_sigma,
    const float* __restrict__ ln1_g, const float* __restrict__ ln1_b,
    const float* __restrict__ ln2_g, const float* __restrict__ ln2_b,
    const float* __restrict__ bf1, const float* __restrict__ bf2,
    const float* __restrict__ alphap, const float* __restrict__ tempp,
    float* __restrict__ out)
{
    // arena: kbuf 32x264 f16 (8448) | vbuf 256x40 f16 (10240) = 18688 f16
    // per-wave scratch (GEMM phases only) aliases arena at wv*4672 (16x264)
    __shared__ __align__(16) _Float16 arena[18688];
    __shared__ __align__(16) _Float16 tp[4 * 640];   // per-wave P: 16x40

    const int tid = threadIdx.x, lane = tid & 63, wv = tid >> 6;
    const int l15 = lane & 15, quad = lane >> 4;
    const int blk = blockIdx.x;
    const int b = ((blk >> 6) << 3) | (blk & 7);   // same-b blocks share XCD slot
    const int g = (blk >> 3) & 7;
    const int i0 = g * 16;
    const int iw = i0 + wv * 4 + quad;             // intent of this lane's rows

    _Float16* kbuf = arena;
    _Float16* vbuf = arena + 8448;
    _Float16* scr  = arena + wv * 4672;
    _Float16* tpw  = tp + wv * 640;

    // ---- init slots in C-layout registers
    f32x4 sl[16];
#pragma unroll
    for (int u = 0; u < 16; u++) {
        int col = u * 16 + l15;
#pragma unroll
        for (int reg = 0; reg < 4; reg++) {
            sl[u][reg] = slot_mu[reg * 256 + col]
                + noise[(((size_t)iw * BSZ + b) * 4 + reg) * 256 + col] * slot_sigma[reg * 256 + col];
        }
    }

    const _Float16* kB = k16 + (size_t)b * 2048 * 256;
    const _Float16* vB = vT16 + (size_t)b * 256 * 2048;

    for (int it = 0; it < 3; it++) {
        // ---- transpose slots -> scr (f16), hoist A-frags
#pragma unroll
        for (int u = 0; u < 16; u++)
#pragma unroll
            for (int reg = 0; reg < 4; reg++)
                scr[(quad * 4 + reg) * 264 + u * 16 + l15] = (_Float16)sl[u][reg];
        f16x8 af[8];
#pragma unroll
        for (int ks = 0; ks < 8; ks++)
            af[ks] = *(const f16x8*)&scr[l15 * 264 + ks * 32 + quad * 8];

        // ---- Wqs: q = (slots@Wqs + qint2) * 1/16 -> scr (overwrites slots copy)
        for (int nt = 0; nt < 16; nt++) {
            f32x4 cc = {0.f, 0.f, 0.f, 0.f};
#pragma unroll
            for (int ks = 0; ks < 8; ks++)
                cc = MFMA16(af[ks], *(const f16x8*)(wqsT + (size_t)(nt * 16 + l15) * 256 + ks * 32 + quad * 8), cc);
            float qi = qint2[(size_t)iw * 256 + nt * 16 + l15];
#pragma unroll
            for (int reg = 0; reg < 4; reg++)
                scr[(quad * 4 + reg) * 264 + nt * 16 + l15] = (_Float16)((cc[reg] + qi) * 0.0625f);
        }
        f16x8 aq[8];
#pragma unroll
        for (int ks = 0; ks < 8; ks++)
            aq[ks] = *(const f16x8*)&scr[l15 * 264 + ks * 32 + quad * 8];

        // ---- attention: 64 chunks of 32 s, wave-local online softmax
        f32x4 ov[16];
#pragma unroll
        for (int u = 0; u < 16; u++) ov[u] = (f32x4){0.f, 0.f, 0.f, 0.f};
        float m_[4] = {-1e30f, -1e30f, -1e30f, -1e30f};
        float l_[4] = {0.f, 0.f, 0.f, 0.f};

        __syncthreads();   // arena -> staging mode

        for (int st = 0; st < 64; st++) {
            const int s0 = st * 32;
            // stage k (32x256) + vT (256x32) cooperatively
            {
                f16x8 kv[8];
#pragma unroll
                for (int i2 = 0; i2 < 4; i2++) {
                    int u = tid + i2 * 256;
                    kv[i2]     = *(const f16x8*)(kB + (size_t)(s0 + (u >> 5)) * 256 + (u & 31) * 8);
                    kv[4 + i2] = *(const f16x8*)(vB + (size_t)(u >> 2) * 2048 + s0 + (u & 3) * 8);
                }
#pragma unroll
                for (int i2 = 0; i2 < 4; i2++) {
                    int u = tid + i2 * 256;
                    *(f16x8*)&kbuf[(u >> 5) * 264 + (u & 31) * 8] = kv[i2];
                    *(f16x8*)&vbuf[(u >> 2) * 40 + (u & 3) * 8]   = kv[4 + i2];
                }
            }
            __syncthreads();

            // logits (2 n-tiles x 8 k-frags)
            f32x4 cl[2];
#pragma unroll
            for (int nt = 0; nt < 2; nt++) {
                cl[nt] = (f32x4){0.f, 0.f, 0.f, 0.f};
#pragma unroll
                for (int ks = 0; ks < 8; ks++)
                    cl[nt] = MFMA16(aq[ks], *(const f16x8*)&kbuf[(nt * 16 + l15) * 264 + ks * 32 + quad * 8], cl[nt]);
            }
            // online softmax (per-quad rows, shuffles over l15 bits only)
            float al[4];
#pragma unroll
            for (int reg = 0; reg < 4; reg++) {
                float tm = fmaxf(cl[0][reg], cl[1][reg]);
#pragma unroll
                for (int msk = 1; msk <= 8; msk <<= 1) tm = fmaxf(tm, __shfl_xor(tm, msk, 64));
                float mn = fmaxf(m_[reg], tm);
                al[reg] = __expf(m_[reg] - mn);
                m_[reg] = mn;
            }
            float ps[4] = {0.f, 0.f, 0.f, 0.f};
#pragma unroll
            for (int nt = 0; nt < 2; nt++)
#pragma unroll
                for (int reg = 0; reg < 4; reg++) {
                    float p = __expf(cl[nt][reg] - m_[reg]);
                    ps[reg] += p;
                    tpw[(quad * 4 + reg) * 40 + nt * 16 + l15] = (_Float16)p;
                }
#pragma unroll
            for (int reg = 0; reg < 4; reg++) {
                float s = ps[reg];
#pragma unroll
                for (int msk = 1; msk <= 8; msk <<= 1) s += __shfl_xor(s, msk, 64);
                l_[reg] = l_[reg] * al[reg] + s;
            }
#pragma unroll
            for (int u = 0; u < 16; u++)
#pragma unroll
                for (int reg = 0; reg < 4; reg++) ov[u][reg] *= al[reg];
            // PV: A = P (wave-local LDS transpose), B = staged vT
            f16x8 ap = *(const f16x8*)&tpw[l15 * 40 + quad * 8];
#pragma unroll
            for (int u = 0; u < 16; u++)
                ov[u] = MFMA16(ap, *(const f16x8*)&vbuf[(u * 16 + l15) * 40 + quad * 8], ov[u]);
            __syncthreads();   // before next chunk overwrites kbuf/vbuf
        }

        // ---- residual + LN1 (in C-layout registers)
#pragma unroll
        for (int reg = 0; reg < 4; reg++) l_[reg] = 1.0f / l_[reg];
#pragma unroll
        for (int u = 0; u < 16; u++)
#pragma unroll
            for (int reg = 0; reg < 4; reg++) sl[u][reg] += ov[u][reg] * l_[reg];

        float s1[4] = {0.f, 0.f, 0.f, 0.f}, s2[4] = {0.f, 0.f, 0.f, 0.f};
#pragma unroll
        for (int u = 0; u < 16; u++)
#pragma unroll
            for (int reg = 0; reg < 4; reg++) { s1[reg] += sl[u][reg]; s2[reg] += sl[u][reg] * sl[u][reg]; }
#pragma unroll
        for (int reg = 0; reg < 4; reg++)
#pragma unroll
            for (int msk = 1; msk <= 8; msk <<= 1) {
                s1[reg] += __shfl_xor(s1[reg], msk, 64);
                s2[reg] += __shfl_xor(s2[reg], msk, 64);
            }
        float mean[4], rstd[4];
#pragma unroll
        for (int reg = 0; reg < 4; reg++) {
            mean[reg] = s1[reg] * (1.f / 256.f);
            rstd[reg] = rsqrtf(s2[reg] * (1.f / 256.f) - mean[reg] * mean[reg] + 1e-5f);
        }
#pragma unroll
        for (int u = 0; u < 16; u++) {
            float g1 = ln1_g[u * 16 + l15], b1 = ln1_b[u * 16 + l15];
#pragma unroll
            for (int reg = 0; reg < 4; reg++)
                sl[u][reg] = (sl[u][reg] - mean[reg]) * rstd[reg] * g1 + b1;
        }
        // ---- LN2 -> h -> scr (arena free again: all waves past chunk loop)
        float t1[4] = {0.f, 0.f, 0.f, 0.f}, t2[4] = {0.f, 0.f, 0.f, 0.f};
#pragma unroll
        for (int u = 0; u < 16; u++)
#pragma unroll
            for (int reg = 0; reg < 4; reg++) { t1[reg] += sl[u][reg]; t2[reg] += sl[u][reg] * sl[u][reg]; }
#pragma unroll
        for (int reg = 0; reg < 4; reg++)
#pragma unroll
            for (int msk = 1; msk <= 8; msk <<= 1) {
                t1[reg] += __shfl_xor(t1[reg], msk, 64);
                t2[reg] += __shfl_xor(t2[reg], msk, 64);
            }
        float mean2[4], rstd2[4];
#pragma unroll
        for (int reg = 0; reg < 4; reg++) {
            mean2[reg] = t1[reg] * (1.f / 256.f);
            rstd2[reg] = rsqrtf(t2[reg] * (1.f / 256.f) - mean2[reg] * mean2[reg] + 1e-5f);
        }
#pragma unroll
        for (int u = 0; u < 16; u++) {
            float g2 = ln2_g[u * 16 + l15], b2 = ln2_b[u * 16 + l15];
#pragma unroll
            for (int reg = 0; reg < 4; reg++)
                scr[(quad * 4 + reg) * 264 + u * 16 + l15] =
                    (_Float16)((sl[u][reg] - mean2[reg]) * rstd2[reg] * g2 + b2);
        }
        f16x8 ah[8];
#pragma unroll
        for (int ks = 0; ks < 8; ks++)
            ah[ks] = *(const f16x8*)&scr[l15 * 264 + ks * 32 + quad * 8];

        // ---- FFN in 2 hidden halves (act reuses scr after ah hoisted)
        f32x4 c2[16];
#pragma unroll
        for (int u = 0; u < 16; u++) c2[u] = (f32x4){0.f, 0.f, 0.f, 0.f};
        for (int half = 0; half < 2; half++) {
            for (int nt = 0; nt < 16; nt++) {
                int hc = half * 256 + nt * 16 + l15;
                f32x4 ca = {0.f, 0.f, 0.f, 0.f};
#pragma unroll
                for (int ks = 0; ks < 8; ks++)
                    ca = MFMA16(ah[ks], *(const f16x8*)(wf1T + (size_t)hc * 256 + ks * 32 + quad * 8), ca);
                float bb = bf1[hc];
#pragma unroll
                for (int reg = 0; reg < 4; reg++) {
                    float xg = ca[reg] + bb;
                    scr[(quad * 4 + reg) * 264 + nt * 16 + l15] =
                        (_Float16)(0.5f * xg * (1.f + erff(xg * 0.70710678118654752f)));
                }
            }
            f16x8 aa[8];
#pragma unroll
            for (int ks = 0; ks < 8; ks++)
                aa[ks] = *(const f16x8*)&scr[l15 * 264 + ks * 32 + quad * 8];
#pragma unroll
            for (int u = 0; u < 16; u++)
#pragma unroll
                for (int ks = 0; ks < 8; ks++)
                    c2[u] = MFMA16(aa[ks], *(const f16x8*)(wf2T + (size_t)(u * 16 + l15) * 512 + half * 256 + ks * 32 + quad * 8), c2[u]);
        }
#pragma unroll
        for (int u = 0; u < 16; u++) {
            float bb2 = bf2[u * 16 + l15];
#pragma unroll
            for (int reg = 0; reg < 4; reg++) sl[u][reg] += c2[u][reg] + bb2;
        }
        // no barrier needed: next iter touches only per-wave scr until the
        // pre-staging __syncthreads
    }

    // ---- final scoring (all wave-local; quad = intent, reg = slot)
    float qnv[16];
#pragma unroll
    for (int u = 0; u < 16; u++) qnv[u] = qn[(size_t)iw * 256 + u * 16 + l15];
    float st4[4];
#pragma unroll
    for (int reg = 0; reg < 4; reg++) {
        float ss = 0.f, sq = 0.f;
#pragma unroll
        for (int u = 0; u < 16; u++) { ss += sl[u][reg] * sl[u][reg]; sq += sl[u][reg] * qnv[u]; }
#pragma unroll
        for (int msk = 1; msk <= 8; msk <<= 1) {
            ss += __shfl_xor(ss, msk, 64);
            sq += __shfl_xor(sq, msk, 64);
        }
        st4[reg] = sq / fmaxf(sqrtf(ss), 1e-12f);
    }
    float mx = fmaxf(fmaxf(st4[0], st4[1]), fmaxf(st4[2], st4[3]));
    float e0 = __expf(st4[0] - mx), e1 = __expf(st4[1] - mx);
    float e2 = __expf(st4[2] - mx), e3 = __expf(st4[3] - mx);
    float inv = 1.f / (e0 + e1 + e2 + e3);
    float ssm = 0.f, sqn = 0.f, cq = 0.f;
#pragma unroll
    for (int u = 0; u < 16; u++) {
        float sm = (e0 * sl[u][0] + e1 * sl[u][1] + e2 * sl[u][2] + e3 * sl[u][3]) * inv;
        ssm += sm * sm;
        sqn += sm * qnv[u];
        cq  += clsn[(size_t)b * 256 + u * 16 + l15] * qnv[u];
    }
#pragma unroll
    for (int msk = 1; msk <= 8; msk <<= 1) {
        ssm += __shfl_xor(ssm, msk, 64);
        sqn += __shfl_xor(sqn, msk, 64);
        cq  += __shfl_xor(cq,  msk, 64);
    }
    if (l15 == 0) {
        float score = cq + alphap[0] * sqn / fmaxf(sqrtf(ssm), 1e-12f);
        out[(size_t)b * NI + iw] = score / fmaxf(tempp[0], 1e-4f);
    }
}

// ---------------------------------------------------------------------------
extern "C" void kernel_launch(void* const* d_in, const int* in_sizes, int n_in,
                              void* d_out, int out_size, void* d_ws, size_t ws_size,
                              hipStream_t stream)
{
    const float* tokens     = (const float*)d_in[0];
    const float* cls_embed  = (const float*)d_in[1];
    const float* intent_q   = (const float*)d_in[2];
    const float* noise      = (const float*)d_in[3];
    const float* Wk  = (const float*)d_in[4];
    const float* bk  = (const float*)d_in[5];
    const float* Wv  = (const float*)d_in[6];
    const float* bv  = (const float*)d_in[7];
    const float* Wqs = (const float*)d_in[8];
    const float* bqs = (const float*)d_in[9];
    const float* Wqi = (const float*)d_in[10];
    const float* bqi = (const float*)d_in[11];
    const float* ln1g = (const float*)d_in[12];
    const float* ln1b = (const float*)d_in[13];
    const float* ln2g = (const float*)d_in[14];
    const float* ln2b = (const float*)d_in[15];
    const float* Wf1 = (const float*)d_in[16];
    const float* bf1 = (const float*)d_in[17];
    const float* Wf2 = (const float*)d_in[18];
    const float* bf2 = (const float*)d_in[19];
    const float* slot_mu    = (const float*)d_in[20];
    const float* slot_sigma = (const float*)d_in[21];
    const float* alphap = (const float*)d_in[22];
    const float* tempp  = (const float*)d_in[23];
    float* out = (float*)d_out;

    char* base = (char*)d_ws;
    _Float16* tok16 = (_Float16*)(base);                       // 33554432 B
    _Float16* k16   = (_Float16*)(base + 33554432u);           // 33554432 B
    _Float16* vT16  = (_Float16*)(base + 67108864u);           // 33554432 B
    _Float16* wkT   = (_Float16*)(base + 100663296u);          // 131072 B
    _Float16* wvT   = (_Float16*)(base + 100794368u);
    _Float16* wqsT  = (_Float16*)(base + 100925440u);
    _Float16* wf1T  = (_Float16*)(base + 101056512u);          // 262144 B
    _Float16* wf2T  = (_Float16*)(base + 101318656u);          // 262144 B
    float* qint2 = (float*)(base + 101580800u);                // 131072 B
    float* qnb   = (float*)(base + 101711872u);                // 131072 B
    float* clsn  = (float*)(base + 101843968u);                // 32768 B

    tok_convert<<<2048, 256, 0, stream>>>(tokens, tok16);
    prep<<<1696, 256, 0, stream>>>(Wk, Wv, Wqs, Wf1, Wf2, intent_q, Wqi, bqi, bqs,
                                   cls_embed, wkT, wvT, wqsT, wf1T, wf2T,
                                   qint2, qnb, clsn);
    k_proj<<<2048, 64, 0, stream>>>(tok16, wkT, bk, k16);
    v_proj<<<2048, 64, 0, stream>>>(tok16, wvT, bv, vT16);
    slot_attn<<<256, 256, 0, stream>>>(k16, vT16, wqsT, wf1T, wf2T, qint2, qnb, clsn,
                                       noise, slot_mu, slot_sigma, ln1g, ln1b, ln2g, ln2b,
                                       bf1, bf2, alphap, tempp, out);
}